// Round 7
// baseline (272.548 us; speedup 1.0000x reference)
//
#include <hip/hip_runtime.h>
#include <math.h>

#define NCLS 92
#define NTGT 2048
#define ROWS 16     // rows (b,q) per block
#define NPASS 4     // 256 thr * 2 tgt * 4 passes = 2048 targets

typedef float vfloat2 __attribute__((ext_vector_type(2)));

// v_rcp_f32 + v_mul_f32 (avoid IEEE div sequence)
__device__ __forceinline__ float fast_div(float a, float b) {
    return a * __builtin_amdgcn_rcpf(b);
}

__global__ __launch_bounds__(256, 4) void matcher_cost_kernel(
    const float* __restrict__ logits,   // [BQ, 92]
    const float* __restrict__ pboxes,   // [BQ, 4]  cxcywh
    const int*   __restrict__ tlabels,  // [T]
    const float* __restrict__ tboxes,   // [T, 4]   cxcywh
    float* __restrict__ out,            // [BQ, T]
    int BQ)
{
    const int row0 = blockIdx.x * ROWS;
    const int tid  = threadIdx.x;
    const int rlim = min(ROWS, BQ - row0);

    __shared__ float s_prob[ROWS][NCLS + 1];  // stride 93 words
    __shared__ float s_pb[ROWS][12];          // px0,py0,px1,py1 | parea,pcx,pcy,pw | ph

    // ---- 16 softmaxes in parallel: 16-lane group g handles row g ----
    {
        const int g = tid >> 4;
        const int l = tid & 15;
        const int gr = (g < rlim) ? g : 0;
        const float* lrow = logits + (long)(row0 + gr) * NCLS;
        float v[6];
        float m = -INFINITY;
        #pragma unroll
        for (int k = 0; k < 6; ++k) {
            const int c = l + k * 16;
            v[k] = (c < NCLS) ? lrow[c] : -INFINITY;
            m = fmaxf(m, v[k]);
        }
        #pragma unroll
        for (int s = 8; s >= 1; s >>= 1) m = fmaxf(m, __shfl_xor(m, s, 16));
        float sum = 0.0f;
        #pragma unroll
        for (int k = 0; k < 6; ++k) {
            const int c = l + k * 16;
            v[k] = (c < NCLS) ? expf(v[k] - m) : 0.0f;
            sum += v[k];
        }
        #pragma unroll
        for (int s = 8; s >= 1; s >>= 1) sum += __shfl_xor(sum, s, 16);
        const float rs = 1.0f / sum;   // once per row, exact
        #pragma unroll
        for (int k = 0; k < 6; ++k) {
            const int c = l + k * 16;
            if (c < NCLS) s_prob[g][c] = v[k] * rs;
        }
    }
    // ---- pred boxes -> xyxy + area, staged in LDS ----
    if (tid < ROWS) {
        const int r = (tid < rlim) ? tid : 0;
        const float4 pb = *(const float4*)(pboxes + (long)(row0 + r) * 4);
        const float px0 = pb.x - 0.5f * pb.z, py0 = pb.y - 0.5f * pb.w;
        const float px1 = pb.x + 0.5f * pb.z, py1 = pb.y + 0.5f * pb.w;
        *(float4*)&s_pb[tid][0] = make_float4(px0, py0, px1, py1);
        *(float4*)&s_pb[tid][4] = make_float4((px1 - px0) * (py1 - py0), pb.x, pb.y, pb.z);
        s_pb[tid][8] = pb.w;
    }
    __syncthreads();

    float* oblk = out + (long)row0 * NTGT;

    #pragma unroll
    for (int pass = 0; pass < NPASS; ++pass) {
        const int t = pass * 512 + tid * 2;       // 2 targets per thread
        const int2 lab = *(const int2*)(tlabels + t);
        const int labs[2] = {lab.x, lab.y};

        float tx0[2], ty0[2], tx1[2], ty1[2], tarea[2], tcx[2], tcy[2], tw[2], th[2];
        #pragma unroll
        for (int j = 0; j < 2; ++j) {
            const float4 tb = *(const float4*)(tboxes + (long)(t + j) * 4);
            tcx[j] = tb.x; tcy[j] = tb.y; tw[j] = tb.z; th[j] = tb.w;
            tx0[j] = tb.x - 0.5f * tb.z; ty0[j] = tb.y - 0.5f * tb.w;
            tx1[j] = tb.x + 0.5f * tb.z; ty1[j] = tb.y + 0.5f * tb.w;
            tarea[j] = (tx1[j] - tx0[j]) * (ty1[j] - ty0[j]);
        }

        auto body = [&](int r) {
            const float4 p0 = *(const float4*)&s_pb[r][0];   // px0 py0 px1 py1 (broadcast)
            const float4 p1 = *(const float4*)&s_pb[r][4];   // parea pcx pcy pw
            const float  ph = s_pb[r][8];
            float c[2];
            #pragma unroll
            for (int j = 0; j < 2; ++j) {
                const float cc = -s_prob[r][labs[j]];

                const float cb = fabsf(p1.y - tcx[j]) + fabsf(p1.z - tcy[j])
                               + fabsf(p1.w - tw[j]) + fabsf(ph - th[j]);

                const float xl = fmaxf(p0.x, tx0[j]), yt = fmaxf(p0.y, ty0[j]);
                const float xr = fminf(p0.z, tx1[j]), yb = fminf(p0.w, ty1[j]);
                const float iw = fmaxf(xr - xl, 0.0f), ih = fmaxf(yb - yt, 0.0f);
                const float inter = iw * ih;
                const float uni = p1.x + tarea[j] - inter;
                const float iou = fast_div(inter, uni);

                // enclosing box: ew,eh provably >= 0 (ex1>=px1>px0>=ex0) -> no clamps
                const float ex0 = fminf(p0.x, tx0[j]), ey0 = fminf(p0.y, ty0[j]);
                const float ex1 = fmaxf(p0.z, tx1[j]), ey1 = fmaxf(p0.w, ty1[j]);
                const float earea = (ex1 - ex0) * (ey1 - ey0);
                const float giou = iou - fast_div(earea - uni, earea);

                c[j] = cc + 5.0f * cb - 2.0f * giou;
            }
            vfloat2 cv;
            cv.x = c[0]; cv.y = c[1];
            __builtin_nontemporal_store(cv, (vfloat2*)(oblk + (long)r * NTGT + t));
        };

        if (rlim == ROWS) {
            #pragma unroll 4
            for (int r = 0; r < ROWS; ++r) body(r);   // clean path: no per-iter branch
        } else {
            for (int r = 0; r < rlim; ++r) body(r);
        }
    }
}

extern "C" void kernel_launch(void* const* d_in, const int* in_sizes, int n_in,
                              void* d_out, int out_size, void* d_ws, size_t ws_size,
                              hipStream_t stream) {
    const float* logits  = (const float*)d_in[0];   // [28800, 92]
    const float* pboxes  = (const float*)d_in[1];   // [28800, 4]
    const int*   tlabels = (const int*)  d_in[2];   // [2048]
    const float* tboxes  = (const float*)d_in[3];   // [2048, 4]
    float* out = (float*)d_out;                     // [28800, 2048]

    const int BQ = in_sizes[1] / 4;                 // 28800 rows
    const int nblk = (BQ + ROWS - 1) / ROWS;        // 1800
    matcher_cost_kernel<<<nblk, 256, 0, stream>>>(logits, pboxes, tlabels, tboxes, out, BQ);
}

// Round 8
// 268.750 us; speedup vs baseline: 1.0141x; 1.0141x over previous
//
#include <hip/hip_runtime.h>
#include <math.h>

#define NCLS 92
#define NTGT 2048
#define ROWS 16     // rows (b,q) per block

typedef float vfloat4 __attribute__((ext_vector_type(4)));

// v_rcp_f32 + v_mul_f32 (avoid IEEE div sequence)
__device__ __forceinline__ float fast_div(float a, float b) {
    return a * __builtin_amdgcn_rcpf(b);
}

__global__ __launch_bounds__(256) void matcher_cost_kernel(
    const float* __restrict__ logits,   // [BQ, 92]
    const float* __restrict__ pboxes,   // [BQ, 4]  cxcywh
    const int*   __restrict__ tlabels,  // [T]
    const float* __restrict__ tboxes,   // [T, 4]   cxcywh
    float* __restrict__ out,            // [BQ, T]
    int BQ)
{
    const int row0 = blockIdx.x * ROWS;
    const int tid  = threadIdx.x;
    const int rlim = min(ROWS, BQ - row0);

    __shared__ float s_prob[ROWS][NCLS + 1];  // stride 93 words

    // ---- 16 softmaxes in parallel: 16-lane group g handles row g ----
    {
        const int g = tid >> 4;
        const int l = tid & 15;
        const int gr = (g < rlim) ? g : 0;
        const float* lrow = logits + (long)(row0 + gr) * NCLS;
        float v[6];
        float m = -INFINITY;
        #pragma unroll
        for (int k = 0; k < 6; ++k) {
            const int c = l + k * 16;
            v[k] = (c < NCLS) ? lrow[c] : -INFINITY;
            m = fmaxf(m, v[k]);
        }
        #pragma unroll
        for (int s = 8; s >= 1; s >>= 1) m = fmaxf(m, __shfl_xor(m, s, 16));
        float sum = 0.0f;
        #pragma unroll
        for (int k = 0; k < 6; ++k) {
            const int c = l + k * 16;
            v[k] = (c < NCLS) ? expf(v[k] - m) : 0.0f;
            sum += v[k];
        }
        #pragma unroll
        for (int s = 8; s >= 1; s >>= 1) sum += __shfl_xor(sum, s, 16);
        const float rs = 1.0f / sum;   // once per row, exact
        #pragma unroll
        for (int k = 0; k < 6; ++k) {
            const int c = l + k * 16;
            if (c < NCLS) s_prob[g][c] = v[k] * rs;
        }
    }
    __syncthreads();

    float* oblk = out + (long)row0 * NTGT;

    #pragma unroll
    for (int pass = 0; pass < 2; ++pass) {
        const int t = pass * 1024 + tid * 4;
        const int4 lab = *(const int4*)(tlabels + t);
        const int labs[4] = {lab.x, lab.y, lab.z, lab.w};

        float tx0[4], ty0[4], tx1[4], ty1[4], tarea[4], tcx[4], tcy[4], tw[4], th[4];
        #pragma unroll
        for (int j = 0; j < 4; ++j) {
            const float4 tb = *(const float4*)(tboxes + (long)(t + j) * 4);
            tcx[j] = tb.x; tcy[j] = tb.y; tw[j] = tb.z; th[j] = tb.w;
            tx0[j] = tb.x - 0.5f * tb.z; ty0[j] = tb.y - 0.5f * tb.w;
            tx1[j] = tb.x + 0.5f * tb.z; ty1[j] = tb.y + 0.5f * tb.w;
            tarea[j] = (tx1[j] - tx0[j]) * (ty1[j] - ty0[j]);
        }

        auto body = [&](int r) {
            // wave-uniform global read -> s_load_dwordx4 (scalar cache), no LDS
            const float4 pb = *(const float4*)(pboxes + (long)(row0 + r) * 4);
            const float px0 = pb.x - 0.5f * pb.z, py0 = pb.y - 0.5f * pb.w;
            const float px1 = pb.x + 0.5f * pb.z, py1 = pb.y + 0.5f * pb.w;
            const float parea = (px1 - px0) * (py1 - py0);

            float c[4];
            #pragma unroll
            for (int j = 0; j < 4; ++j) {
                const float cc = -s_prob[r][labs[j]];

                const float cb = fabsf(pb.x - tcx[j]) + fabsf(pb.y - tcy[j])
                               + fabsf(pb.z - tw[j]) + fabsf(pb.w - th[j]);

                const float xl = fmaxf(px0, tx0[j]), yt = fmaxf(py0, ty0[j]);
                const float xr = fminf(px1, tx1[j]), yb = fminf(py1, ty1[j]);
                const float iw = fmaxf(xr - xl, 0.0f), ih = fmaxf(yb - yt, 0.0f);
                const float inter = iw * ih;
                const float uni = parea + tarea[j] - inter;
                const float iou = fast_div(inter, uni);

                // enclosing box: ew,eh provably >= 0 -> no clamps needed
                const float ex0 = fminf(px0, tx0[j]), ey0 = fminf(py0, ty0[j]);
                const float ex1 = fmaxf(px1, tx1[j]), ey1 = fmaxf(py1, ty1[j]);
                const float earea = (ex1 - ex0) * (ey1 - ey0);
                const float giou = iou - fast_div(earea - uni, earea);

                c[j] = cc + 5.0f * cb - 2.0f * giou;
            }
            vfloat4 cv;
            cv.x = c[0]; cv.y = c[1]; cv.z = c[2]; cv.w = c[3];
            __builtin_nontemporal_store(cv, (vfloat4*)(oblk + (long)r * NTGT + t));
        };

        if (rlim == ROWS) {
            #pragma unroll 4
            for (int r = 0; r < ROWS; ++r) body(r);   // clean path: no per-iter branch
        } else {
            for (int r = 0; r < rlim; ++r) body(r);
        }
    }
}

extern "C" void kernel_launch(void* const* d_in, const int* in_sizes, int n_in,
                              void* d_out, int out_size, void* d_ws, size_t ws_size,
                              hipStream_t stream) {
    const float* logits  = (const float*)d_in[0];   // [28800, 92]
    const float* pboxes  = (const float*)d_in[1];   // [28800, 4]
    const int*   tlabels = (const int*)  d_in[2];   // [2048]
    const float* tboxes  = (const float*)d_in[3];   // [2048, 4]
    float* out = (float*)d_out;                     // [28800, 2048]

    const int BQ = in_sizes[1] / 4;                 // 28800 rows
    const int nblk = (BQ + ROWS - 1) / ROWS;        // 1800
    matcher_cost_kernel<<<nblk, 256, 0, stream>>>(logits, pboxes, tlabels, tboxes, out, BQ);
}